// Round 5
// baseline (438.534 us; speedup 1.0000x reference)
//
#include <hip/hip_runtime.h>

// CustomGraphConv (fp32 in/out, int64 edge_index runtime-detected):
//   msg[e,o] = sum_{a,i} ea[e,a]*W[a,o,i]*x[src_e,i]; scatter-add to dst; relu(+bias).
// Factorized: y[n,o,a] = sum_i W[a,o,i]*x[n,i]  (bf16, 25.6 MB, L3-resident),
// stage2: 4 threads/edge, each dot8(ea[e,:], y[src,o,:]) for 4 o's + atomicAdd.
// fp32 accumulation directly in d_out; stage1 also zeroes d_out (no memset dispatch).

#define IN_C 16
#define OUT_C 16
#define NA 8

typedef unsigned short u16;

__device__ __forceinline__ float bfbits(unsigned hi) {
    union { unsigned u; float f; } c; c.u = hi; return c.f;
}
__device__ __forceinline__ u16 f2bf(float f) {
    union { float f; unsigned u; } c; c.f = f;
    unsigned u = c.u + (0x7fffu + ((c.u >> 16) & 1u));   // RNE
    return (u16)(u >> 16);
}
__device__ __forceinline__ float dot4(float4 a, float4 b) {
    float s = a.x * b.x;
    s = fmaf(a.y, b.y, s);
    s = fmaf(a.z, b.z, s);
    s = fmaf(a.w, b.w, s);
    return s;
}

// ---------- stage 1: y_bf16[n][o][a] = dot(W[a,o,:], x[n,:]), 2 nodes/thread;
//            also zeroes out[] and (block 0) detects int64 edge_index ----------
__global__ void __launch_bounds__(256) k_stage1(
    const float* __restrict__ x, const float* __restrict__ W,
    const int* __restrict__ ei, long long n_edges,
    u16* __restrict__ y, float* __restrict__ out,
    int* __restrict__ flag, int n_nodes) {
    // int64 detection (block 0): odd 32-bit words within first 2E words are all
    // zero iff int64 (high halves of indices < 2^31). int32: random node ids.
    __shared__ int s_nz;
    if (blockIdx.x == 0) {
        if (threadIdx.x == 0) s_nz = 0;
        __syncthreads();
        long long lim = 2 * n_edges;
        long long step = (n_edges / 256) | 1;
        long long pos = 1 + 2 * (long long)threadIdx.x * step;
        if (pos < lim && ei[pos] != 0) atomicOr(&s_nz, 1);
        __syncthreads();
        if (threadIdx.x == 0) flag[0] = (s_nz == 0) ? 1 : 0;   // 1 => int64
    }

    // W[a][o][i] staged as float4: Wl[o][a*4+q] (q = i/4). Row stride 33 float4
    // = 132 dwords ≡ 4 (mod 32): lanes o and o+8 share a bank (2-way, free).
    __shared__ float4 Wl[OUT_C][33];
    for (int k = threadIdx.x; k < 512; k += 256) {
        int a = k >> 6, o = (k >> 2) & 15, q = k & 3;
        Wl[o][a * 4 + q] = reinterpret_cast<const float4*>(W)[k];
    }
    __syncthreads();

    int npairs = (n_nodes + 1) >> 1;
    int idx = blockIdx.x * 256 + threadIdx.x;
    if (idx >= npairs * OUT_C) return;
    int p = idx >> 4, o = idx & 15;
    int n0 = p * 2;
    bool has1 = (n0 + 1) < n_nodes;

    const float4* xp0 = reinterpret_cast<const float4*>(x + (size_t)n0 * IN_C);
    float4 X0[4] = {xp0[0], xp0[1], xp0[2], xp0[3]};
    float4 X1[4];
    if (has1) {
        const float4* xp1 = reinterpret_cast<const float4*>(x + (size_t)(n0 + 1) * IN_C);
        X1[0] = xp1[0]; X1[1] = xp1[1]; X1[2] = xp1[2]; X1[3] = xp1[3];
    }

    union { uint4 u; u16 h[8]; } pk0, pk1;
#pragma unroll
    for (int a = 0; a < NA; ++a) {
        float4 w0 = Wl[o][a * 4 + 0], w1 = Wl[o][a * 4 + 1];
        float4 w2 = Wl[o][a * 4 + 2], w3 = Wl[o][a * 4 + 3];
        float s0 = dot4(w0, X0[0]) + dot4(w1, X0[1]) + dot4(w2, X0[2]) + dot4(w3, X0[3]);
        pk0.h[a] = f2bf(s0);
        if (has1) {
            float s1 = dot4(w0, X1[0]) + dot4(w1, X1[1]) + dot4(w2, X1[2]) + dot4(w3, X1[3]);
            pk1.h[a] = f2bf(s1);
        }
    }
    reinterpret_cast<uint4*>(y + ((size_t)n0 * OUT_C + o) * NA)[0] = pk0.u;
    out[(size_t)n0 * OUT_C + o] = 0.f;
    if (has1) {
        reinterpret_cast<uint4*>(y + ((size_t)(n0 + 1) * OUT_C + o) * NA)[0] = pk1.u;
        out[(size_t)(n0 + 1) * OUT_C + o] = 0.f;
    }
}

// ---------- stage 2: 4 threads/edge; thread q handles channels 4q..4q+3 ----------
__global__ void __launch_bounds__(256) k_stage2(
    const int* __restrict__ ei, const float* __restrict__ ea,
    const u16* __restrict__ y, float* __restrict__ out,
    const int* __restrict__ flag, long long n_edges) {
    long long gid = (long long)blockIdx.x * 256 + threadIdx.x;
    if (gid >= n_edges * 4) return;
    long long e = gid >> 2;
    int q = (int)(gid & 3);
    int src, dst;
    if (flag[0]) { src = ei[2 * e]; dst = ei[2 * (n_edges + e)]; }
    else         { src = ei[e];     dst = ei[n_edges + e]; }

    const float4* ap = reinterpret_cast<const float4*>(ea + e * NA);
    float4 a0 = ap[0], a1 = ap[1];
    float av[NA] = {a0.x, a0.y, a0.z, a0.w, a1.x, a1.y, a1.z, a1.w};

    // y row for channels 4q..4q+3: 64 B contiguous; lanes q=0..3 cover the 256 B row.
    const uint4* yp = reinterpret_cast<const uint4*>(y + ((size_t)src * OUT_C + q * 4) * NA);
    float s[4];
#pragma unroll
    for (int j = 0; j < 4; ++j) {
        uint4 yu = yp[j];
        float t = bfbits(yu.x << 16) * av[0];
        t = fmaf(bfbits(yu.x & 0xffff0000u), av[1], t);
        t = fmaf(bfbits(yu.y << 16),         av[2], t);
        t = fmaf(bfbits(yu.y & 0xffff0000u), av[3], t);
        t = fmaf(bfbits(yu.z << 16),         av[4], t);
        t = fmaf(bfbits(yu.z & 0xffff0000u), av[5], t);
        t = fmaf(bfbits(yu.w << 16),         av[6], t);
        t = fmaf(bfbits(yu.w & 0xffff0000u), av[7], t);
        s[j] = t;
    }
    float* op = out + (size_t)dst * OUT_C + q * 4;
#pragma unroll
    for (int j = 0; j < 4; ++j) unsafeAtomicAdd(op + j, s[j]);
}

// ---------- fallback (tiny ws): direct einsum, assumes int64 ----------
__global__ void __launch_bounds__(256) k_direct(
    const float* __restrict__ x, const int* __restrict__ ei,
    const float* __restrict__ ea, const float* __restrict__ W,
    float* __restrict__ out, long long n_edges) {
    __shared__ float Wl[OUT_C][129];
    for (int k = threadIdx.x; k < NA * OUT_C * IN_C; k += 256) {
        int a = k >> 8, o = (k >> 4) & 15, i = k & 15;
        Wl[o][a * IN_C + i] = W[k];
    }
    __syncthreads();
    long long idx = (long long)blockIdx.x * 256 + threadIdx.x;
    if (idx >= n_edges * OUT_C) return;
    long long e = idx >> 4;
    int o = (int)(idx & 15);
    int src = ei[2 * e], dst = ei[2 * (n_edges + e)];
    const float4* ap = reinterpret_cast<const float4*>(ea + e * NA);
    float4 a0 = ap[0], a1 = ap[1];
    float av[NA] = {a0.x, a0.y, a0.z, a0.w, a1.x, a1.y, a1.z, a1.w};
    const float4* xp = reinterpret_cast<const float4*>(x + (size_t)src * IN_C);
    float4 x0 = xp[0], x1 = xp[1], x2 = xp[2], x3 = xp[3];
    float xv[16] = {x0.x, x0.y, x0.z, x0.w, x1.x, x1.y, x1.z, x1.w,
                    x2.x, x2.y, x2.z, x2.w, x3.x, x3.y, x3.z, x3.w};
    float s = 0.f;
#pragma unroll
    for (int a = 0; a < NA; ++a) {
        float d = 0.f;
#pragma unroll
        for (int i = 0; i < IN_C; ++i) d = fmaf(Wl[o][a * IN_C + i], xv[i], d);
        s = fmaf(av[a], d, s);
    }
    unsafeAtomicAdd(out + (size_t)dst * OUT_C + o, s);
}

// ---------- finalize: in-place out = relu(out + bias) ----------
__global__ void __launch_bounds__(256) k_bias_relu(
    const float* __restrict__ bias, float* __restrict__ out, int total4) {
    int idx = blockIdx.x * 256 + threadIdx.x;
    if (idx >= total4) return;
    int j0 = (idx & 3) * 4;
    const float4 b = reinterpret_cast<const float4*>(bias + j0)[0];
    float4* op = reinterpret_cast<float4*>(out) + idx;
    float4 v = op[0];
    v.x = fmaxf(v.x + b.x, 0.f);
    v.y = fmaxf(v.y + b.y, 0.f);
    v.z = fmaxf(v.z + b.z, 0.f);
    v.w = fmaxf(v.w + b.w, 0.f);
    op[0] = v;
}

extern "C" void kernel_launch(void* const* d_in, const int* in_sizes, int n_in,
                              void* d_out, int out_size, void* d_ws, size_t ws_size,
                              hipStream_t stream) {
    const float* x    = (const float*)d_in[0];   // [N,16] f32
    const int*   ei   = (const int*)d_in[1];     // [2,E] int64 (runtime-verified) or int32
    const float* ea   = (const float*)d_in[2];   // [E,8] f32
    const float* W    = (const float*)d_in[3];   // [8,16,16] f32
    const float* bias = (const float*)d_in[4];   // [16] f32
    float* out = (float*)d_out;

    int n_nodes = in_sizes[0] / IN_C;
    long long n_edges = in_sizes[2] / NA;

    size_t y_bytes = (size_t)n_nodes * OUT_C * NA * sizeof(u16);  // 25.6 MB
    if (ws_size >= 64 + y_bytes) {
        int* flag = (int*)d_ws;
        u16* y = (u16*)((char*)d_ws + 64);
        int npairs = (n_nodes + 1) >> 1;
        int t1 = npairs * OUT_C;
        k_stage1<<<(t1 + 255) / 256, 256, 0, stream>>>(x, W, ei, n_edges, y, out, flag, n_nodes);
        long long tE = n_edges * 4;
        k_stage2<<<(int)((tE + 255) / 256), 256, 0, stream>>>(ei, ea, y, out, flag, n_edges);
    } else {
        hipMemsetAsync(d_out, 0, (size_t)n_nodes * OUT_C * sizeof(float), stream);
        long long tE = n_edges * OUT_C;
        k_direct<<<(int)((tE + 255) / 256), 256, 0, stream>>>(x, ei, ea, W, out, n_edges);
    }

    int t4 = (n_nodes * OUT_C) / 4;
    k_bias_relu<<<(t4 + 255) / 256, 256, 0, stream>>>(bias, out, t4);
}

// Round 6
// 224.533 us; speedup vs baseline: 1.9531x; 1.9531x over previous
//
#include <hip/hip_runtime.h>

// CustomGraphConv (fp32 in/out, int64 edge_index runtime-detected):
//   msg[e,o] = sum_{a,i} ea[e,a]*W[a,o,i]*x[src_e,i]; scatter-add to dst; relu(+bias).
// Factorized: y[n,o,a] = sum_i W[a,o,i]*x[n,i]  (bf16, 25.6 MB, mostly L3-resident).
// stage2 (R4-proven layout): 16 threads/edge, lane o computes dot8(ea[e,:], y[src,o,:])
// and issues ONE atomicAdd at out[dst*16+o] — consecutive lanes hit consecutive
// addresses (contiguous 64 B per edge) so TCC coalesces atomic writes (4 B/atomic
// effective; R5's 4-lane variant showed 16 B/atomic = 4x WRITE_SIZE and 3x dur).
// fp32 accumulation directly in d_out; stage1 also zeroes d_out.

#define IN_C 16
#define OUT_C 16
#define NA 8

typedef unsigned short u16;

__device__ __forceinline__ float bfbits(unsigned hi) {
    union { unsigned u; float f; } c; c.u = hi; return c.f;
}
__device__ __forceinline__ u16 f2bf(float f) {
    union { float f; unsigned u; } c; c.f = f;
    unsigned u = c.u + (0x7fffu + ((c.u >> 16) & 1u));   // RNE
    return (u16)(u >> 16);
}
__device__ __forceinline__ float dot4(float4 a, float4 b) {
    float s = a.x * b.x;
    s = fmaf(a.y, b.y, s);
    s = fmaf(a.z, b.z, s);
    s = fmaf(a.w, b.w, s);
    return s;
}

// ---------- stage 1: y_bf16[n][o][a] = dot(W[a,o,:], x[n,:]), 2 nodes/thread;
//            zeroes out[]; block 0 detects int64 edge_index ----------
__global__ void __launch_bounds__(256) k_stage1(
    const float* __restrict__ x, const float* __restrict__ W,
    const int* __restrict__ ei, long long n_edges,
    u16* __restrict__ y, float* __restrict__ out,
    int* __restrict__ flag, int n_nodes) {
    __shared__ int s_nz;
    if (blockIdx.x == 0) {
        if (threadIdx.x == 0) s_nz = 0;
        __syncthreads();
        long long lim = 2 * n_edges;
        long long step = (n_edges / 256) | 1;
        long long pos = 1 + 2 * (long long)threadIdx.x * step;
        if (pos < lim && ei[pos] != 0) atomicOr(&s_nz, 1);
        __syncthreads();
        if (threadIdx.x == 0) flag[0] = (s_nz == 0) ? 1 : 0;   // 1 => int64
    }

    // W[a][o][i] as float4: Wl[o][a*4+q]. Row stride 33 float4 = 132 dwords.
    __shared__ float4 Wl[OUT_C][33];
    for (int k = threadIdx.x; k < 512; k += 256) {
        int a = k >> 6, o = (k >> 2) & 15, q = k & 3;
        Wl[o][a * 4 + q] = reinterpret_cast<const float4*>(W)[k];
    }
    __syncthreads();

    int npairs = (n_nodes + 1) >> 1;
    int idx = blockIdx.x * 256 + threadIdx.x;
    if (idx >= npairs * OUT_C) return;
    int p = idx >> 4, o = idx & 15;
    int n0 = p * 2;
    bool has1 = (n0 + 1) < n_nodes;

    const float4* xp0 = reinterpret_cast<const float4*>(x + (size_t)n0 * IN_C);
    float4 X0[4] = {xp0[0], xp0[1], xp0[2], xp0[3]};
    float4 X1[4];
    if (has1) {
        const float4* xp1 = reinterpret_cast<const float4*>(x + (size_t)(n0 + 1) * IN_C);
        X1[0] = xp1[0]; X1[1] = xp1[1]; X1[2] = xp1[2]; X1[3] = xp1[3];
    }

    union { uint4 u; u16 h[8]; } pk0, pk1;
#pragma unroll
    for (int a = 0; a < NA; ++a) {
        float4 w0 = Wl[o][a * 4 + 0], w1 = Wl[o][a * 4 + 1];
        float4 w2 = Wl[o][a * 4 + 2], w3 = Wl[o][a * 4 + 3];
        float s0 = dot4(w0, X0[0]) + dot4(w1, X0[1]) + dot4(w2, X0[2]) + dot4(w3, X0[3]);
        pk0.h[a] = f2bf(s0);
        if (has1) {
            float s1 = dot4(w0, X1[0]) + dot4(w1, X1[1]) + dot4(w2, X1[2]) + dot4(w3, X1[3]);
            pk1.h[a] = f2bf(s1);
        }
    }
    reinterpret_cast<uint4*>(y + ((size_t)n0 * OUT_C + o) * NA)[0] = pk0.u;
    out[(size_t)n0 * OUT_C + o] = 0.f;
    if (has1) {
        reinterpret_cast<uint4*>(y + ((size_t)(n0 + 1) * OUT_C + o) * NA)[0] = pk1.u;
        out[(size_t)(n0 + 1) * OUT_C + o] = 0.f;
    }
}

// ---------- stage 2 (R4 layout): 16 threads/edge, lane o -> channel o ----------
__global__ void __launch_bounds__(256) k_stage2(
    const int* __restrict__ ei, const float* __restrict__ ea,
    const u16* __restrict__ y, float* __restrict__ out,
    const int* __restrict__ flag, long long n_edges) {
    long long idx = (long long)blockIdx.x * 256 + threadIdx.x;
    if (idx >= n_edges * OUT_C) return;
    long long e = idx >> 4;
    int o = (int)(idx & 15);
    int src, dst;
    if (flag[0]) { src = ei[2 * e]; dst = ei[2 * (n_edges + e)]; }
    else         { src = ei[e];     dst = ei[n_edges + e]; }

    const float4* ap = reinterpret_cast<const float4*>(ea + e * NA);
    float4 a0 = ap[0], a1 = ap[1];
    uint4 yu = reinterpret_cast<const uint4*>(y + ((size_t)src * OUT_C + o) * NA)[0];

    float s =      bfbits(yu.x << 16)        * a0.x;
    s = fmaf(bfbits(yu.x & 0xffff0000u), a0.y, s);
    s = fmaf(bfbits(yu.y << 16),         a0.z, s);
    s = fmaf(bfbits(yu.y & 0xffff0000u), a0.w, s);
    s = fmaf(bfbits(yu.z << 16),         a1.x, s);
    s = fmaf(bfbits(yu.z & 0xffff0000u), a1.y, s);
    s = fmaf(bfbits(yu.w << 16),         a1.z, s);
    s = fmaf(bfbits(yu.w & 0xffff0000u), a1.w, s);

    unsafeAtomicAdd(out + (size_t)dst * OUT_C + o, s);
}

// ---------- fallback (tiny ws): direct einsum, assumes int64 ----------
__global__ void __launch_bounds__(256) k_direct(
    const float* __restrict__ x, const int* __restrict__ ei,
    const float* __restrict__ ea, const float* __restrict__ W,
    float* __restrict__ out, long long n_edges) {
    __shared__ float Wl[OUT_C][129];
    for (int k = threadIdx.x; k < NA * OUT_C * IN_C; k += 256) {
        int a = k >> 8, o = (k >> 4) & 15, i = k & 15;
        Wl[o][a * IN_C + i] = W[k];
    }
    __syncthreads();
    long long idx = (long long)blockIdx.x * 256 + threadIdx.x;
    if (idx >= n_edges * OUT_C) return;
    long long e = idx >> 4;
    int o = (int)(idx & 15);
    int src = ei[2 * e], dst = ei[2 * (n_edges + e)];
    const float4* ap = reinterpret_cast<const float4*>(ea + e * NA);
    float4 a0 = ap[0], a1 = ap[1];
    float av[NA] = {a0.x, a0.y, a0.z, a0.w, a1.x, a1.y, a1.z, a1.w};
    const float4* xp = reinterpret_cast<const float4*>(x + (size_t)src * IN_C);
    float4 x0 = xp[0], x1 = xp[1], x2 = xp[2], x3 = xp[3];
    float xv[16] = {x0.x, x0.y, x0.z, x0.w, x1.x, x1.y, x1.z, x1.w,
                    x2.x, x2.y, x2.z, x2.w, x3.x, x3.y, x3.z, x3.w};
    float s = 0.f;
#pragma unroll
    for (int a = 0; a < NA; ++a) {
        float d = 0.f;
#pragma unroll
        for (int i = 0; i < IN_C; ++i) d = fmaf(Wl[o][a * IN_C + i], xv[i], d);
        s = fmaf(av[a], d, s);
    }
    unsafeAtomicAdd(out + (size_t)dst * OUT_C + o, s);
}

// ---------- finalize: in-place out = relu(out + bias) ----------
__global__ void __launch_bounds__(256) k_bias_relu(
    const float* __restrict__ bias, float* __restrict__ out, int total4) {
    int idx = blockIdx.x * 256 + threadIdx.x;
    if (idx >= total4) return;
    int j0 = (idx & 3) * 4;
    const float4 b = reinterpret_cast<const float4*>(bias + j0)[0];
    float4* op = reinterpret_cast<float4*>(out) + idx;
    float4 v = op[0];
    v.x = fmaxf(v.x + b.x, 0.f);
    v.y = fmaxf(v.y + b.y, 0.f);
    v.z = fmaxf(v.z + b.z, 0.f);
    v.w = fmaxf(v.w + b.w, 0.f);
    op[0] = v;
}

extern "C" void kernel_launch(void* const* d_in, const int* in_sizes, int n_in,
                              void* d_out, int out_size, void* d_ws, size_t ws_size,
                              hipStream_t stream) {
    const float* x    = (const float*)d_in[0];   // [N,16] f32
    const int*   ei   = (const int*)d_in[1];     // [2,E] int64 (runtime-verified) or int32
    const float* ea   = (const float*)d_in[2];   // [E,8] f32
    const float* W    = (const float*)d_in[3];   // [8,16,16] f32
    const float* bias = (const float*)d_in[4];   // [16] f32
    float* out = (float*)d_out;

    int n_nodes = in_sizes[0] / IN_C;
    long long n_edges = in_sizes[2] / NA;

    size_t y_bytes = (size_t)n_nodes * OUT_C * NA * sizeof(u16);  // 25.6 MB
    if (ws_size >= 64 + y_bytes) {
        int* flag = (int*)d_ws;
        u16* y = (u16*)((char*)d_ws + 64);
        int npairs = (n_nodes + 1) >> 1;
        int t1 = npairs * OUT_C;
        k_stage1<<<(t1 + 255) / 256, 256, 0, stream>>>(x, W, ei, n_edges, y, out, flag, n_nodes);
        long long tE = n_edges * OUT_C;
        k_stage2<<<(int)((tE + 255) / 256), 256, 0, stream>>>(ei, ea, y, out, flag, n_edges);
    } else {
        hipMemsetAsync(d_out, 0, (size_t)n_nodes * OUT_C * sizeof(float), stream);
        long long tE = n_edges * OUT_C;
        k_direct<<<(int)((tE + 255) / 256), 256, 0, stream>>>(x, ei, ea, W, out, n_edges);
    }

    int t4 = (n_nodes * OUT_C) / 4;
    k_bias_relu<<<(t4 + 255) / 256, 256, 0, stream>>>(bias, out, t4);
}